// Round 10
// baseline (139.306 us; speedup 1.0000x reference)
//
#include <hip/hip_runtime.h>

// NonLocalLayer  B=8, C=128, MID=64, OUT=128, T=4, N=512, TN=2048
// R27: R26 + (a) stats holds TWO 64-k B-frag sets per block (128 k/block):
// theta staging + barriers per unit work halved, grid (nb,16*qsplit);
// (b) g stored column-PERMUTED within each 64-k tile (proj write) so attn's
// PV B-frags are single ds_read_b128 instead of 2x ds_read_b64 (16->8 LDS
// reads/kt/lane). perm: k -> (k>>5)*32 + ((k&15)>>2)*8 + ((k>>4)&1)*4 + (k&3).
// attn QK path / yred / refsc unchanged from R26.

constexpr int NL75_TN  = 2048;
constexpr int NL75_MID = 64;
constexpr int NL75_C   = 128;
constexpr float NL75_L2E = 1.4426950408889634f;

typedef __attribute__((ext_vector_type(8))) short nl75_bf8;
typedef __attribute__((ext_vector_type(4))) float nl75_f4;

__device__ __forceinline__ unsigned short nl75_f2b(float f) {
  unsigned x = __float_as_uint(f);
  return (unsigned short)((x + 0x7fffu + ((x >> 16) & 1u)) >> 16);
}

__device__ __forceinline__ unsigned int nl75_pkbf16(float lo, float hi) {
  unsigned int r;
  asm("v_cvt_pk_bf16_f32 %0, %1, %2" : "=v"(r) : "v"(lo), "v"(hi));
  return r;
}

__device__ __forceinline__ float nl75_exp2(float x) {
  float r;
  asm("v_exp_f32 %0, %1" : "=v"(r) : "v"(x));
  return r;
}

typedef const __attribute__((address_space(1))) unsigned int* nl75_gp;
typedef __attribute__((address_space(3))) unsigned int* nl75_lp;
__device__ __forceinline__ void nl75_gld16(const void* g, void* l) {
  __builtin_amdgcn_global_load_lds((nl75_gp)g, (nl75_lp)l, 16, 0, 0);
}

// stage a 64x64 bf16 tile into LDS: lds[row][c] = src[row][c ^ ((row&7)<<3)]
// (linear LDS dest = wave-uniform base + lane*16; swizzle on the SOURCE).
__device__ __forceinline__ void nl75_stage64(const unsigned short* src,
                                             size_t pitch, unsigned short* lds,
                                             int tid) {
  const int w = tid >> 6, lane = tid & 63;
#pragma unroll
  for (int r = 0; r < 2; r++) {
    const int slot = r * 256 + w * 64 + lane;
    const int row = slot >> 3, x = slot & 7;
    const unsigned short* s =
        src + (size_t)row * pitch + ((x * 8) ^ ((row & 7) << 3));
    nl75_gld16(s, lds + (size_t)(r * 256 + w * 64) * 8);
  }
}

__global__ void NonLocalLayer_75771813036638_kernel() {}

// ---------------- projections -> bf16 frag-ready layouts --------------------
// grid (nb, 3, 32), block 256. 8m x 2q register tile per thread.
// thT/phT: [bl][x][m] bf16. g: [bl][m][k] bf16 with k PERMUTED per 64-tile.
__global__ void nl75_proj(const float* pc, const float* w0, const float* b0,
                          const float* w1, const float* b1, const float* w2,
                          const float* b2, unsigned short* thT,
                          unsigned short* phT, unsigned short* gN, int bOff,
                          int nb) {
  __shared__ float wT[NL75_C][68];
  const int bl = blockIdx.x, pj = blockIdx.y, qt = blockIdx.z;
  const int b = bOff + bl;
  const float* wp = (pj == 0) ? w0 : (pj == 1) ? w1 : w2;
  const float* bp = (pj == 0) ? b0 : (pj == 1) ? b1 : b2;
  const int tid = threadIdx.x;
  for (int i = tid; i < NL75_MID * NL75_C; i += 256)
    wT[i & 127][i >> 7] = wp[i];
  __syncthreads();
  const int qg = tid & 31, mg = tid >> 5;  // 32 q-pairs x 8 m-groups
  const int q = qt * 64 + qg * 2, m0 = mg * 8;
  const float* pcb = pc + (long long)b * NL75_C * NL75_TN + q;
  float acc[8][2];
#pragma unroll
  for (int i = 0; i < 8; i++) acc[i][0] = acc[i][1] = bp[m0 + i];
#pragma unroll 4
  for (int c = 0; c < NL75_C; c++) {
    const float2 p = *(const float2*)&pcb[(size_t)c * NL75_TN];
    float w8[8];
    *(float4*)&w8[0] = *(const float4*)&wT[c][m0];
    *(float4*)&w8[4] = *(const float4*)&wT[c][m0 + 4];
#pragma unroll
    for (int i = 0; i < 8; i++) {
      acc[i][0] = fmaf(w8[i], p.x, acc[i][0]);
      acc[i][1] = fmaf(w8[i], p.y, acc[i][1]);
    }
  }
  if (pj < 2) {
    unsigned int u[8];
#pragma unroll
    for (int i = 0; i < 4; i++) {
      u[i] = nl75_pkbf16(fmaxf(acc[2 * i][0], 0.0f),
                         fmaxf(acc[2 * i + 1][0], 0.0f));
      u[4 + i] = nl75_pkbf16(fmaxf(acc[2 * i][1], 0.0f),
                             fmaxf(acc[2 * i + 1][1], 0.0f));
    }
    unsigned short* dst =
        (pj == 0 ? thT : phT) + ((size_t)bl * NL75_TN + q) * 64 + m0;
    *reinterpret_cast<uint4*>(dst) = *reinterpret_cast<uint4*>(&u[0]);
    *reinterpret_cast<uint4*>(dst + 64) = *reinterpret_cast<uint4*>(&u[4]);
  } else {
    // permuted column within the 64-k tile so PV B-frags are b128-contiguous.
    // even-k pairs stay adjacent -> ushort2 writes preserved.
    const int kin = q & 63;
    const int np = (kin >> 5) * 32 + (((kin & 15) >> 2) << 3) +
                   (((kin >> 4) & 1) << 2) + (kin & 3);
    const size_t gq = (size_t)(q & ~63) | np;
#pragma unroll
    for (int i = 0; i < 8; i++) {
      ushort2 v;
      v.x = nl75_f2b(fmaxf(acc[i][0], 0.0f));
      v.y = nl75_f2b(fmaxf(acc[i][1], 0.0f));
      *(ushort2*)&gN[((size_t)bl * NL75_MID + m0 + i) * NL75_TN + gq] = v;
    }
  }
}

// ------------- partial softmax denominators (max-free, 128-k blocks) --------
// grid (nb, 16*qsplit), block 256. LDS 16 KB. Two 64-k B-frag sets/block.
__global__ void nl75_stats(const unsigned short* thT, const unsigned short* phT,
                           float* Sp, int nb, int qsplit) {
  __shared__ unsigned short thL[2][64 * 64];
  const int bl = blockIdx.x;
  const int kt = blockIdx.y & 15, qs = blockIdx.y >> 4;
  const int tid = threadIdx.x, lane = tid & 63, w = tid >> 6;
  const int l15 = lane & 15, quad = lane >> 4;
  const int k0 = kt * 128;
  const unsigned short* thB = thT + (size_t)bl * NL75_TN * 64;
  const unsigned short* phB = phT + (size_t)bl * NL75_TN * 64;
  const size_t kra = (size_t)(k0 + w * 16 + l15) * 64;
  const size_t krb = (size_t)(k0 + 64 + w * 16 + l15) * 64;
  const nl75_bf8 b0a = *(const nl75_bf8*)&phB[kra + quad * 8];
  const nl75_bf8 b1a = *(const nl75_bf8*)&phB[kra + 32 + quad * 8];
  const nl75_bf8 b0b = *(const nl75_bf8*)&phB[krb + quad * 8];
  const nl75_bf8 b1b = *(const nl75_bf8*)&phB[krb + 32 + quad * 8];
  const int qtN = 32 / qsplit, qtBeg = qs * qtN;
  nl75_stage64(thB + (size_t)(qtBeg * 64) * 64, 64, thL[0], tid);
  __syncthreads();
  float Sa = 0.0f, Sb = 0.0f;
  for (int qt = qtBeg; qt < qtBeg + qtN; qt++) {
    const int cur = (qt - qtBeg) & 1;
    if (qt + 1 < qtBeg + qtN)
      nl75_stage64(thB + (size_t)((qt + 1) * 64) * 64, 64, thL[cur ^ 1], tid);
    __builtin_amdgcn_s_setprio(1);
#pragma unroll
    for (int q16 = 0; q16 < 4; q16++) {
      const int qr = q16 * 16 + l15;
      const int sw = (qr & 7) << 3;
      const nl75_bf8 a0 = *(const nl75_bf8*)&thL[cur][qr * 64 + ((quad * 8) ^ sw)];
      const nl75_bf8 a1 =
          *(const nl75_bf8*)&thL[cur][qr * 64 + ((32 + quad * 8) ^ sw)];
      nl75_f4 ca = {0.0f, 0.0f, 0.0f, 0.0f};
      ca = __builtin_amdgcn_mfma_f32_16x16x32_bf16(a0, b0a, ca, 0, 0, 0);
      ca = __builtin_amdgcn_mfma_f32_16x16x32_bf16(a1, b1a, ca, 0, 0, 0);
      nl75_f4 cb = {0.0f, 0.0f, 0.0f, 0.0f};
      cb = __builtin_amdgcn_mfma_f32_16x16x32_bf16(a0, b0b, cb, 0, 0, 0);
      cb = __builtin_amdgcn_mfma_f32_16x16x32_bf16(a1, b1b, cb, 0, 0, 0);
      Sa += (nl75_exp2(ca[0] * NL75_L2E) + nl75_exp2(ca[1] * NL75_L2E)) +
            (nl75_exp2(ca[2] * NL75_L2E) + nl75_exp2(ca[3] * NL75_L2E));
      Sb += (nl75_exp2(cb[0] * NL75_L2E) + nl75_exp2(cb[1] * NL75_L2E)) +
            (nl75_exp2(cb[2] * NL75_L2E) + nl75_exp2(cb[3] * NL75_L2E));
    }
    __builtin_amdgcn_s_setprio(0);
    __syncthreads();
  }
  // combine the 4 quads (lanes k, k+16, k+32, k+48 share a column)
  Sa += __shfl_xor(Sa, 16);
  Sa += __shfl_xor(Sa, 32);
  Sb += __shfl_xor(Sb, 16);
  Sb += __shfl_xor(Sb, 32);
  if (quad == 0) {
    const long long base = ((long long)(qs * nb + bl)) * NL75_TN + k0;
    Sp[base + w * 16 + l15] = Sa;
    Sp[base + 64 + w * 16 + l15] = Sb;
  }
}

// ------------- attention apply + PV (dbuf-LDS phi/g, fused ek) --------------
// grid 1D (16*ksplit*nb), block 256, bl fastest (XCD pinning). LDS 40 KB.
// Prologue computes ek[k] = log2(sum_qs Sp) for this block's k-range while
// the first global_load_lds tiles are in flight. g is column-permuted so
// PV B-frags are single b128 LDS reads.
__global__ void nl75_attn(const unsigned short* thT, const unsigned short* phT,
                          const unsigned short* gN, const float* Sp,
                          float* yPart, int nb, int ksplit, int qsplit) {
  __shared__ unsigned short phL[2][64 * 64];
  __shared__ unsigned short gL[2][64 * 64];
  __shared__ float ekL[2048];
  const int wg = blockIdx.x;
  const int bl = wg % nb;
  const int rest = wg / nb;
  const int qt = rest & 15, ks = rest >> 4;
  const int tid = threadIdx.x, lane = tid & 63, w = tid >> 6;
  const int l15 = lane & 15, quad = lane >> 4;
  const int q0 = qt * 128;
  const unsigned short* thB = thT + (size_t)bl * NL75_TN * 64;
  const unsigned short* phB = phT + (size_t)bl * NL75_TN * 64;
  const unsigned short* gB = gN + (size_t)bl * NL75_MID * NL75_TN;
  const int ktN = 32 / ksplit;
  const int ktBeg = ks * ktN, ktEnd = ktBeg + ktN;
  // prologue: stage first tiles (DMA in flight while ek computes below)
  nl75_stage64(phB + (size_t)(ktBeg * 64) * 64, 64, phL[0], tid);
  nl75_stage64(gB + ktBeg * 64, NL75_TN, gL[0], tid);
  // theta frags for the 2 q-tiles (global, linear layout, loaded once)
  nl75_bf8 aq[2][2];
#pragma unroll
  for (int s = 0; s < 2; s++) {
    const size_t qr = (size_t)(q0 + s * 64 + w * 16 + l15) * 64;
    aq[s][0] = *(const nl75_bf8*)&thB[qr + quad * 8];
    aq[s][1] = *(const nl75_bf8*)&thB[qr + 32 + quad * 8];
  }
  // fused sred: ek for this block's k-range (coalesced L2-hit Sp reads)
  const int kRange = ktN * 64;
  for (int kk = tid; kk < kRange; kk += 256) {
    const int k = ktBeg * 64 + kk;
    float S = 0.0f;
    for (int qs = 0; qs < qsplit; qs++)
      S += Sp[((size_t)(qs * nb + bl)) * NL75_TN + k];
    ekL[kk] = __log2f(S);
  }
  nl75_f4 yacc[2][4];
#pragma unroll
  for (int s = 0; s < 2; s++)
#pragma unroll
    for (int i = 0; i < 4; i++) yacc[s][i] = (nl75_f4){0.0f, 0.0f, 0.0f, 0.0f};
  __syncthreads();
  union Frag { nl75_bf8 h; unsigned int u[4]; };
  for (int kt = ktBeg; kt < ktEnd; kt++) {
    const int cur = (kt - ktBeg) & 1;
    if (kt + 1 < ktEnd) {
      nl75_stage64(phB + (size_t)((kt + 1) * 64) * 64, 64, phL[cur ^ 1], tid);
      nl75_stage64(gB + (kt + 1) * 64, NL75_TN, gL[cur ^ 1], tid);
    }
    // ek for this k-tile from LDS (lane needs k = kt*64 + t*16 + quad*4 + r)
    const int ekBase = (kt - ktBeg) * 64;
    nl75_f4 ek[4];
#pragma unroll
    for (int t = 0; t < 4; t++)
      ek[t] = *(const nl75_f4*)&ekL[ekBase + t * 16 + quad * 4];
    __builtin_amdgcn_s_setprio(1);
    // QK swapped: lane holds C'[k = kt*64+t*16+4*quad+r][q = q0+s*64+w*16+l15]
    unsigned int pk[2][8];
#pragma unroll
    for (int t = 0; t < 4; t++) {
      const int krr = t * 16 + l15;
      const int sw = (krr & 7) << 3;
      const nl75_bf8 b0 =
          *(const nl75_bf8*)&phL[cur][krr * 64 + ((quad * 8) ^ sw)];
      const nl75_bf8 b1 =
          *(const nl75_bf8*)&phL[cur][krr * 64 + ((32 + quad * 8) ^ sw)];
#pragma unroll
      for (int s = 0; s < 2; s++) {
        nl75_f4 c = {0.0f, 0.0f, 0.0f, 0.0f};
        c = __builtin_amdgcn_mfma_f32_16x16x32_bf16(b0, aq[s][0], c, 0, 0, 0);
        c = __builtin_amdgcn_mfma_f32_16x16x32_bf16(b1, aq[s][1], c, 0, 0, 0);
        // P = exp(s)/S = exp2(s*log2e - ek)
        pk[s][t * 2 + 0] =
            nl75_pkbf16(nl75_exp2(fmaf(c[0], NL75_L2E, -ek[t][0])),
                        nl75_exp2(fmaf(c[1], NL75_L2E, -ek[t][1])));
        pk[s][t * 2 + 1] =
            nl75_pkbf16(nl75_exp2(fmaf(c[2], NL75_L2E, -ek[t][2])),
                        nl75_exp2(fmaf(c[3], NL75_L2E, -ek[t][3])));
      }
    }
    // PV: A-frag = own pk regs; B-frag = permuted-g rows, single b128 per
    // 32-k chunk (slot 8q+j -> k = 16*(j>>2) + 4*q + (j&3) is contiguous
    // in the permuted layout).
#pragma unroll
    for (int mtile = 0; mtile < 4; mtile++) {
      const int m = mtile * 16 + l15;
      const int sw = (m & 7) << 3;
      const unsigned short* row = &gL[cur][m * 64];
      Frag bg0, bg1;
      bg0.h = *(const nl75_bf8*)&row[(quad * 8) ^ sw];
      bg1.h = *(const nl75_bf8*)&row[(32 + quad * 8) ^ sw];
#pragma unroll
      for (int s = 0; s < 2; s++) {
        Frag a0, a1;
        a0.u[0] = pk[s][0]; a0.u[1] = pk[s][1];
        a0.u[2] = pk[s][2]; a0.u[3] = pk[s][3];
        a1.u[0] = pk[s][4]; a1.u[1] = pk[s][5];
        a1.u[2] = pk[s][6]; a1.u[3] = pk[s][7];
        yacc[s][mtile] = __builtin_amdgcn_mfma_f32_16x16x32_bf16(
            a0.h, bg0.h, yacc[s][mtile], 0, 0, 0);
        yacc[s][mtile] = __builtin_amdgcn_mfma_f32_16x16x32_bf16(
            a1.h, bg1.h, yacc[s][mtile], 0, 0, 0);
      }
    }
    __builtin_amdgcn_s_setprio(0);
    __syncthreads();
  }
  // direct float4 y-store: lane holds y[m][q0 + s*64 + w*16 + quad*4 + r]
  float* yB = yPart + ((size_t)(ks * nb + bl) * NL75_MID) * NL75_TN;
#pragma unroll
  for (int s = 0; s < 2; s++)
#pragma unroll
    for (int mtile = 0; mtile < 4; mtile++) {
      float4 v = make_float4(yacc[s][mtile][0], yacc[s][mtile][1],
                             yacc[s][mtile][2], yacc[s][mtile][3]);
      *(float4*)&yB[(size_t)(mtile * 16 + l15) * NL75_TN + q0 + s * 64 +
                    w * 16 + quad * 4] = v;
    }
}

// ------- streaming ksplit-reduction: y = sum_ks yPart[ks] -------------------
__global__ void nl75_yred(const float* yPart, float* y, int nb, int ksplit) {
  const size_t tot = (size_t)nb * NL75_MID * NL75_TN / 4;
  const size_t stride = tot;
  const float4* src = (const float4*)yPart;
  float4* dst = (float4*)y;
  for (size_t i = (size_t)blockIdx.x * 256 + threadIdx.x; i < tot;
       i += (size_t)gridDim.x * 256) {
    float4 a = src[i];
    for (int ks = 1; ks < ksplit; ks++) {
      float4 b = src[(size_t)ks * stride + i];
      a.x += b.x; a.y += b.y; a.z += b.z; a.w += b.w;
    }
    dst[i] = a;
  }
}

// ------- fused refine GEMM + scatter + residual (coalesced epilogue) --------
// grid (nb, 16, 4), block 256. (unchanged)
__global__ void nl75_refsc(const float* yIn, const float* rW, const float* rB,
                           const float* pc, float* outP, int bOff, int nb,
                           int ksplit) {
  __shared__ float rwS[32][66];
  __shared__ float yS[NL75_MID][132];  // reused as outS[8][516] after GEMM
  const int bl = blockIdx.x, cg = blockIdx.y, t = blockIdx.z;
  const int b = bOff + bl, c0 = cg * 8, tid = threadIdx.x;
  for (int i = tid; i < 32 * NL75_MID; i += 256) {
    int oh = i >> 6, m = i & 63;
    rwS[oh][m] = rW[(long long)(t * 32 + oh) * NL75_MID + m];
  }
  if (ksplit == 1) {
    const float* yB0 = yIn + (size_t)bl * NL75_MID * NL75_TN;
    for (int i = tid; i < NL75_MID * 32; i += 256) {
      int m = i >> 5, r = i & 31;       // r = i16*2 + half
      int i16 = r >> 1, half = r & 1;
      const float4 v = *(const float4*)&yB0[(size_t)m * NL75_TN + i16 * 128 +
                                            c0 + half * 4];
      *(float4*)&yS[m][i16 * 8 + half * 4] = v;
    }
  } else {
    for (int i = tid; i < NL75_MID * 128; i += 256) {
      int m = i >> 7, qi = i & 127;
      int i16 = qi >> 3, cl = qi & 7;
      long long off = (long long)m * NL75_TN + i16 * 128 + c0 + cl;
      float v = 0.0f;
      for (int ks = 0; ks < ksplit; ks++)
        v += yIn[((long long)(ks * nb + bl) * NL75_MID) * NL75_TN + off];
      yS[m][qi] = v;
    }
  }
  __syncthreads();
  const int oh0 = (tid >> 5) * 4;
  const int q4 = (tid & 31) * 4;
  float acc[4][4];
#pragma unroll
  for (int i = 0; i < 4; i++) {
    float bias = rB[t * 32 + oh0 + i];
#pragma unroll
    for (int j = 0; j < 4; j++) acc[i][j] = bias;
  }
  for (int m = 0; m < NL75_MID; m++) {
    float yv[4];
#pragma unroll
    for (int j = 0; j < 4; j++) yv[j] = yS[m][q4 + j];
#pragma unroll
    for (int i = 0; i < 4; i++) {
      float w = rwS[oh0 + i][m];
#pragma unroll
      for (int j = 0; j < 4; j++) acc[i][j] = fmaf(w, yv[j], acc[i][j]);
    }
  }
  __syncthreads();  // all yS reads done before outS overwrite
  float* outS = &yS[0][0];
  const int NP = 516;
#pragma unroll
  for (int i = 0; i < 4; i++) {
    const int oh = oh0 + i;
#pragma unroll
    for (int j = 0; j < 4; j++) {
      const int qi = q4 + j;
      outS[(qi & 7) * NP + oh * 16 + (qi >> 3)] = fmaxf(acc[i][j], 0.0f);
    }
  }
  __syncthreads();
  const size_t obase = (((size_t)b * 128 + c0) * 4 + t) * 512;
#pragma unroll
  for (int ii = 0; ii < 4; ii++) {
    const int fi = ii * 256 + tid;
    const int cl = fi >> 7, n0 = (fi & 127) * 4;
    float4 v = *(const float4*)&outS[cl * NP + n0];
    const size_t gi = obase + (size_t)cl * 4 * 512 + n0;
    const float4 p = *(const float4*)&pc[gi];
    v.x += p.x; v.y += p.y; v.z += p.z; v.w += p.w;
    *(float4*)&outP[gi] = v;
  }
}

extern "C" void kernel_launch(void* const* d_in, const int* in_sizes, int n_in,
                              void* d_out, int out_size, void* d_ws, size_t ws_size,
                              hipStream_t stream) {
  const float* pc = (const float*)d_in[0];
  const float* tw = (const float*)d_in[1];
  const float* tb = (const float*)d_in[2];
  const float* pw = (const float*)d_in[3];
  const float* pb = (const float*)d_in[4];
  const float* gw = (const float*)d_in[5];
  const float* gb = (const float*)d_in[6];
  const float* rw = (const float*)d_in[7];
  const float* rb = (const float*)d_in[8];
  float* out = (float*)d_out;

  const size_t yPB = (size_t)NL75_MID * NL75_TN;  // floats
  auto need = [&](int nb, int qs, int ks) -> size_t {
    return (3ull * nb * NL75_TN * 64 * 2) +
           ((size_t)qs * nb * NL75_TN + ((size_t)ks * nb + nb) * yPB) * 4;
  };

  int nb, qsplit, ksplit;
  if (ws_size >= need(8, 8, 8))      { nb = 8; qsplit = 8; ksplit = 8; }
  else if (ws_size >= need(8, 1, 1)) { nb = 8; qsplit = 1; ksplit = 1; }
  else                               { nb = 1; qsplit = 1; ksplit = 1; }
  const int nloop = 8 / nb;

  unsigned short* thT = (unsigned short*)d_ws;
  unsigned short* phT = thT + (size_t)nb * NL75_TN * 64;
  unsigned short* gN = phT + (size_t)nb * NL75_TN * 64;
  float* Sp = (float*)(gN + (size_t)nb * NL75_MID * NL75_TN);
  float* yPart = Sp + (size_t)qsplit * nb * NL75_TN;
  float* yFull = (ksplit > 1) ? yPart + (size_t)ksplit * nb * yPB : yPart;

  for (int l = 0; l < nloop; l++) {
    const int bOff = l * nb;
    nl75_proj<<<dim3(nb, 3, 32), 256, 0, stream>>>(pc, tw, tb, pw, pb, gw, gb,
                                                   thT, phT, gN, bOff, nb);
    nl75_stats<<<dim3(nb, 16 * qsplit), 256, 0, stream>>>(thT, phT, Sp, nb,
                                                          qsplit);
    nl75_attn<<<dim3(16 * ksplit * nb), 256, 0, stream>>>(
        thT, phT, gN, Sp, yPart, nb, ksplit, qsplit);
    if (ksplit > 1) {
      nl75_yred<<<dim3(1024), 256, 0, stream>>>(yPart, yFull, nb, ksplit);
      nl75_refsc<<<dim3(nb, 16, 4), 256, 0, stream>>>(yFull, rw, rb, pc, out,
                                                      bOff, nb, 1);
    } else {
      nl75_refsc<<<dim3(nb, 16, 4), 256, 0, stream>>>(yPart, rw, rb, pc, out,
                                                      bOff, nb, 1);
    }
  }
}

// Round 11
// 136.333 us; speedup vs baseline: 1.0218x; 1.0218x over previous
//
#include <hip/hip_runtime.h>

// NonLocalLayer  B=8, C=128, MID=64, OUT=128, T=4, N=512, TN=2048
// R28: R27 with attn restructured to 512-thread blocks (8 waves x 16 q-rows;
// old s-loop halves become waves 4-7). LDS 40 KB unchanged -> 4 blocks/CU x
// 8 waves = 32 waves/CU (max occupancy; was 16). Per-thread state halved,
// __launch_bounds__(512,8) pins VGPR<=64. Dataflow/QK/PV math, permuted-g,
// stats/proj/yred/refsc all unchanged from R27.

constexpr int NL75_TN  = 2048;
constexpr int NL75_MID = 64;
constexpr int NL75_C   = 128;
constexpr float NL75_L2E = 1.4426950408889634f;

typedef __attribute__((ext_vector_type(8))) short nl75_bf8;
typedef __attribute__((ext_vector_type(4))) float nl75_f4;

__device__ __forceinline__ unsigned short nl75_f2b(float f) {
  unsigned x = __float_as_uint(f);
  return (unsigned short)((x + 0x7fffu + ((x >> 16) & 1u)) >> 16);
}

__device__ __forceinline__ unsigned int nl75_pkbf16(float lo, float hi) {
  unsigned int r;
  asm("v_cvt_pk_bf16_f32 %0, %1, %2" : "=v"(r) : "v"(lo), "v"(hi));
  return r;
}

__device__ __forceinline__ float nl75_exp2(float x) {
  float r;
  asm("v_exp_f32 %0, %1" : "=v"(r) : "v"(x));
  return r;
}

typedef const __attribute__((address_space(1))) unsigned int* nl75_gp;
typedef __attribute__((address_space(3))) unsigned int* nl75_lp;
__device__ __forceinline__ void nl75_gld16(const void* g, void* l) {
  __builtin_amdgcn_global_load_lds((nl75_gp)g, (nl75_lp)l, 16, 0, 0);
}

// stage a 64x64 bf16 tile into LDS with 256 threads (2 x 16B per thread):
// lds[row][c] = src[row][c ^ ((row&7)<<3)] (swizzle on the SOURCE).
__device__ __forceinline__ void nl75_stage64(const unsigned short* src,
                                             size_t pitch, unsigned short* lds,
                                             int tid) {
  const int w = tid >> 6, lane = tid & 63;
#pragma unroll
  for (int r = 0; r < 2; r++) {
    const int slot = r * 256 + w * 64 + lane;
    const int row = slot >> 3, x = slot & 7;
    const unsigned short* s =
        src + (size_t)row * pitch + ((x * 8) ^ ((row & 7) << 3));
    nl75_gld16(s, lds + (size_t)(r * 256 + w * 64) * 8);
  }
}

// same, with 512 threads (1 x 16B per thread).
__device__ __forceinline__ void nl75_stage64w(const unsigned short* src,
                                              size_t pitch,
                                              unsigned short* lds, int tid) {
  const int w = tid >> 6;
  const int row = tid >> 3, x = tid & 7;
  const unsigned short* s =
      src + (size_t)row * pitch + ((x * 8) ^ ((row & 7) << 3));
  nl75_gld16(s, lds + (size_t)(w * 64) * 8);
}

__global__ void NonLocalLayer_75771813036638_kernel() {}

// ---------------- projections -> bf16 frag-ready layouts (unchanged) --------
// grid (nb, 3, 32), block 256. 8m x 2q register tile per thread.
// thT/phT: [bl][x][m] bf16. g: [bl][m][k] bf16 with k PERMUTED per 64-tile.
__global__ void nl75_proj(const float* pc, const float* w0, const float* b0,
                          const float* w1, const float* b1, const float* w2,
                          const float* b2, unsigned short* thT,
                          unsigned short* phT, unsigned short* gN, int bOff,
                          int nb) {
  __shared__ float wT[NL75_C][68];
  const int bl = blockIdx.x, pj = blockIdx.y, qt = blockIdx.z;
  const int b = bOff + bl;
  const float* wp = (pj == 0) ? w0 : (pj == 1) ? w1 : w2;
  const float* bp = (pj == 0) ? b0 : (pj == 1) ? b1 : b2;
  const int tid = threadIdx.x;
  for (int i = tid; i < NL75_MID * NL75_C; i += 256)
    wT[i & 127][i >> 7] = wp[i];
  __syncthreads();
  const int qg = tid & 31, mg = tid >> 5;  // 32 q-pairs x 8 m-groups
  const int q = qt * 64 + qg * 2, m0 = mg * 8;
  const float* pcb = pc + (long long)b * NL75_C * NL75_TN + q;
  float acc[8][2];
#pragma unroll
  for (int i = 0; i < 8; i++) acc[i][0] = acc[i][1] = bp[m0 + i];
#pragma unroll 4
  for (int c = 0; c < NL75_C; c++) {
    const float2 p = *(const float2*)&pcb[(size_t)c * NL75_TN];
    float w8[8];
    *(float4*)&w8[0] = *(const float4*)&wT[c][m0];
    *(float4*)&w8[4] = *(const float4*)&wT[c][m0 + 4];
#pragma unroll
    for (int i = 0; i < 8; i++) {
      acc[i][0] = fmaf(w8[i], p.x, acc[i][0]);
      acc[i][1] = fmaf(w8[i], p.y, acc[i][1]);
    }
  }
  if (pj < 2) {
    unsigned int u[8];
#pragma unroll
    for (int i = 0; i < 4; i++) {
      u[i] = nl75_pkbf16(fmaxf(acc[2 * i][0], 0.0f),
                         fmaxf(acc[2 * i + 1][0], 0.0f));
      u[4 + i] = nl75_pkbf16(fmaxf(acc[2 * i][1], 0.0f),
                             fmaxf(acc[2 * i + 1][1], 0.0f));
    }
    unsigned short* dst =
        (pj == 0 ? thT : phT) + ((size_t)bl * NL75_TN + q) * 64 + m0;
    *reinterpret_cast<uint4*>(dst) = *reinterpret_cast<uint4*>(&u[0]);
    *reinterpret_cast<uint4*>(dst + 64) = *reinterpret_cast<uint4*>(&u[4]);
  } else {
    // permuted column within the 64-k tile so PV B-frags are b128-contiguous.
    const int kin = q & 63;
    const int np = (kin >> 5) * 32 + (((kin & 15) >> 2) << 3) +
                   (((kin >> 4) & 1) << 2) + (kin & 3);
    const size_t gq = (size_t)(q & ~63) | np;
#pragma unroll
    for (int i = 0; i < 8; i++) {
      ushort2 v;
      v.x = nl75_f2b(fmaxf(acc[i][0], 0.0f));
      v.y = nl75_f2b(fmaxf(acc[i][1], 0.0f));
      *(ushort2*)&gN[((size_t)bl * NL75_MID + m0 + i) * NL75_TN + gq] = v;
    }
  }
}

// ------------- partial softmax denominators (max-free, 128-k blocks) --------
// grid (nb, 16*qsplit), block 256. LDS 16 KB. (unchanged from R27)
__global__ void nl75_stats(const unsigned short* thT, const unsigned short* phT,
                           float* Sp, int nb, int qsplit) {
  __shared__ unsigned short thL[2][64 * 64];
  const int bl = blockIdx.x;
  const int kt = blockIdx.y & 15, qs = blockIdx.y >> 4;
  const int tid = threadIdx.x, lane = tid & 63, w = tid >> 6;
  const int l15 = lane & 15, quad = lane >> 4;
  const int k0 = kt * 128;
  const unsigned short* thB = thT + (size_t)bl * NL75_TN * 64;
  const unsigned short* phB = phT + (size_t)bl * NL75_TN * 64;
  const size_t kra = (size_t)(k0 + w * 16 + l15) * 64;
  const size_t krb = (size_t)(k0 + 64 + w * 16 + l15) * 64;
  const nl75_bf8 b0a = *(const nl75_bf8*)&phB[kra + quad * 8];
  const nl75_bf8 b1a = *(const nl75_bf8*)&phB[kra + 32 + quad * 8];
  const nl75_bf8 b0b = *(const nl75_bf8*)&phB[krb + quad * 8];
  const nl75_bf8 b1b = *(const nl75_bf8*)&phB[krb + 32 + quad * 8];
  const int qtN = 32 / qsplit, qtBeg = qs * qtN;
  nl75_stage64(thB + (size_t)(qtBeg * 64) * 64, 64, thL[0], tid);
  __syncthreads();
  float Sa = 0.0f, Sb = 0.0f;
  for (int qt = qtBeg; qt < qtBeg + qtN; qt++) {
    const int cur = (qt - qtBeg) & 1;
    if (qt + 1 < qtBeg + qtN)
      nl75_stage64(thB + (size_t)((qt + 1) * 64) * 64, 64, thL[cur ^ 1], tid);
    __builtin_amdgcn_s_setprio(1);
#pragma unroll
    for (int q16 = 0; q16 < 4; q16++) {
      const int qr = q16 * 16 + l15;
      const int sw = (qr & 7) << 3;
      const nl75_bf8 a0 = *(const nl75_bf8*)&thL[cur][qr * 64 + ((quad * 8) ^ sw)];
      const nl75_bf8 a1 =
          *(const nl75_bf8*)&thL[cur][qr * 64 + ((32 + quad * 8) ^ sw)];
      nl75_f4 ca = {0.0f, 0.0f, 0.0f, 0.0f};
      ca = __builtin_amdgcn_mfma_f32_16x16x32_bf16(a0, b0a, ca, 0, 0, 0);
      ca = __builtin_amdgcn_mfma_f32_16x16x32_bf16(a1, b1a, ca, 0, 0, 0);
      nl75_f4 cb = {0.0f, 0.0f, 0.0f, 0.0f};
      cb = __builtin_amdgcn_mfma_f32_16x16x32_bf16(a0, b0b, cb, 0, 0, 0);
      cb = __builtin_amdgcn_mfma_f32_16x16x32_bf16(a1, b1b, cb, 0, 0, 0);
      Sa += (nl75_exp2(ca[0] * NL75_L2E) + nl75_exp2(ca[1] * NL75_L2E)) +
            (nl75_exp2(ca[2] * NL75_L2E) + nl75_exp2(ca[3] * NL75_L2E));
      Sb += (nl75_exp2(cb[0] * NL75_L2E) + nl75_exp2(cb[1] * NL75_L2E)) +
            (nl75_exp2(cb[2] * NL75_L2E) + nl75_exp2(cb[3] * NL75_L2E));
    }
    __builtin_amdgcn_s_setprio(0);
    __syncthreads();
  }
  Sa += __shfl_xor(Sa, 16);
  Sa += __shfl_xor(Sa, 32);
  Sb += __shfl_xor(Sb, 16);
  Sb += __shfl_xor(Sb, 32);
  if (quad == 0) {
    const long long base = ((long long)(qs * nb + bl)) * NL75_TN + k0;
    Sp[base + w * 16 + l15] = Sa;
    Sp[base + 64 + w * 16 + l15] = Sb;
  }
}

// ------------- attention apply + PV (512 threads, 8 waves, max occ.) --------
// grid 1D (16*ksplit*nb), block 512, bl fastest (XCD pinning). LDS 40 KB.
// 4 blocks/CU x 8 waves = 32 waves/CU. Wave w owns q-rows q0 + w*16 + l15.
__launch_bounds__(512, 8)
__global__ void nl75_attn(const unsigned short* thT, const unsigned short* phT,
                          const unsigned short* gN, const float* Sp,
                          float* yPart, int nb, int ksplit, int qsplit) {
  __shared__ unsigned short phL[2][64 * 64];
  __shared__ unsigned short gL[2][64 * 64];
  __shared__ float ekL[2048];
  const int wg = blockIdx.x;
  const int bl = wg % nb;
  const int rest = wg / nb;
  const int qt = rest & 15, ks = rest >> 4;
  const int tid = threadIdx.x, lane = tid & 63, w = tid >> 6;
  const int l15 = lane & 15, quad = lane >> 4;
  const int q0 = qt * 128;
  const unsigned short* thB = thT + (size_t)bl * NL75_TN * 64;
  const unsigned short* phB = phT + (size_t)bl * NL75_TN * 64;
  const unsigned short* gB = gN + (size_t)bl * NL75_MID * NL75_TN;
  const int ktN = 32 / ksplit;
  const int ktBeg = ks * ktN, ktEnd = ktBeg + ktN;
  // prologue: stage first tiles (DMA in flight while ek computes below)
  nl75_stage64w(phB + (size_t)(ktBeg * 64) * 64, 64, phL[0], tid);
  nl75_stage64w(gB + ktBeg * 64, NL75_TN, gL[0], tid);
  // theta frags for this wave's 16 q rows (loaded once)
  nl75_bf8 aq0, aq1;
  {
    const size_t qr = (size_t)(q0 + w * 16 + l15) * 64;
    aq0 = *(const nl75_bf8*)&thB[qr + quad * 8];
    aq1 = *(const nl75_bf8*)&thB[qr + 32 + quad * 8];
  }
  // fused sred: ek for this block's k-range (coalesced L2-hit Sp reads)
  const int kRange = ktN * 64;
  for (int kk = tid; kk < kRange; kk += 512) {
    const int k = ktBeg * 64 + kk;
    float S = 0.0f;
    for (int qs = 0; qs < qsplit; qs++)
      S += Sp[((size_t)(qs * nb + bl)) * NL75_TN + k];
    ekL[kk] = __log2f(S);
  }
  nl75_f4 yacc[4];
#pragma unroll
  for (int i = 0; i < 4; i++) yacc[i] = (nl75_f4){0.0f, 0.0f, 0.0f, 0.0f};
  __syncthreads();
  union Frag { nl75_bf8 h; unsigned int u[4]; };
  for (int kt = ktBeg; kt < ktEnd; kt++) {
    const int cur = (kt - ktBeg) & 1;
    if (kt + 1 < ktEnd) {
      nl75_stage64w(phB + (size_t)((kt + 1) * 64) * 64, 64, phL[cur ^ 1], tid);
      nl75_stage64w(gB + (kt + 1) * 64, NL75_TN, gL[cur ^ 1], tid);
    }
    const int ekBase = (kt - ktBeg) * 64;
    __builtin_amdgcn_s_setprio(1);
    // QK swapped: lane holds C'[k = kt*64+t*16+4*quad+r][q = q0+w*16+l15]
    unsigned int pk[8];
#pragma unroll
    for (int t = 0; t < 4; t++) {
      const int krr = t * 16 + l15;
      const int sw = (krr & 7) << 3;
      const nl75_bf8 b0 =
          *(const nl75_bf8*)&phL[cur][krr * 64 + ((quad * 8) ^ sw)];
      const nl75_bf8 b1 =
          *(const nl75_bf8*)&phL[cur][krr * 64 + ((32 + quad * 8) ^ sw)];
      const nl75_f4 ek = *(const nl75_f4*)&ekL[ekBase + t * 16 + quad * 4];
      nl75_f4 c = {0.0f, 0.0f, 0.0f, 0.0f};
      c = __builtin_amdgcn_mfma_f32_16x16x32_bf16(b0, aq0, c, 0, 0, 0);
      c = __builtin_amdgcn_mfma_f32_16x16x32_bf16(b1, aq1, c, 0, 0, 0);
      // P = exp(s)/S = exp2(s*log2e - ek)
      pk[t * 2 + 0] = nl75_pkbf16(nl75_exp2(fmaf(c[0], NL75_L2E, -ek[0])),
                                  nl75_exp2(fmaf(c[1], NL75_L2E, -ek[1])));
      pk[t * 2 + 1] = nl75_pkbf16(nl75_exp2(fmaf(c[2], NL75_L2E, -ek[2])),
                                  nl75_exp2(fmaf(c[3], NL75_L2E, -ek[3])));
    }
    // PV: A-frag = own pk regs; B-frag = permuted-g rows, single b128 per
    // 32-k chunk (slot relabel k = 16*(j>>2) + 4*q + (j&3) is contiguous).
    Frag a0, a1;
    a0.u[0] = pk[0]; a0.u[1] = pk[1]; a0.u[2] = pk[2]; a0.u[3] = pk[3];
    a1.u[0] = pk[4]; a1.u[1] = pk[5]; a1.u[2] = pk[6]; a1.u[3] = pk[7];
#pragma unroll
    for (int mtile = 0; mtile < 4; mtile++) {
      const int m = mtile * 16 + l15;
      const int sw = (m & 7) << 3;
      const unsigned short* row = &gL[cur][m * 64];
      Frag bg0, bg1;
      bg0.h = *(const nl75_bf8*)&row[(quad * 8) ^ sw];
      bg1.h = *(const nl75_bf8*)&row[(32 + quad * 8) ^ sw];
      yacc[mtile] = __builtin_amdgcn_mfma_f32_16x16x32_bf16(a0.h, bg0.h,
                                                            yacc[mtile], 0, 0, 0);
      yacc[mtile] = __builtin_amdgcn_mfma_f32_16x16x32_bf16(a1.h, bg1.h,
                                                            yacc[mtile], 0, 0, 0);
    }
    __builtin_amdgcn_s_setprio(0);
    __syncthreads();
  }
  // direct float4 y-store: lane holds y[m = mtile*16+l15][q0 + w*16 + quad*4+r]
  float* yB = yPart + ((size_t)(ks * nb + bl) * NL75_MID) * NL75_TN;
#pragma unroll
  for (int mtile = 0; mtile < 4; mtile++) {
    float4 v = make_float4(yacc[mtile][0], yacc[mtile][1], yacc[mtile][2],
                           yacc[mtile][3]);
    *(float4*)&yB[(size_t)(mtile * 16 + l15) * NL75_TN + q0 + w * 16 +
                  quad * 4] = v;
  }
}

// ------- streaming ksplit-reduction: y = sum_ks yPart[ks] -------------------
__global__ void nl75_yred(const float* yPart, float* y, int nb, int ksplit) {
  const size_t tot = (size_t)nb * NL75_MID * NL75_TN / 4;
  const size_t stride = tot;
  const float4* src = (const float4*)yPart;
  float4* dst = (float4*)y;
  for (size_t i = (size_t)blockIdx.x * 256 + threadIdx.x; i < tot;
       i += (size_t)gridDim.x * 256) {
    float4 a = src[i];
    for (int ks = 1; ks < ksplit; ks++) {
      float4 b = src[(size_t)ks * stride + i];
      a.x += b.x; a.y += b.y; a.z += b.z; a.w += b.w;
    }
    dst[i] = a;
  }
}

// ------- fused refine GEMM + scatter + residual (coalesced epilogue) --------
// grid (nb, 16, 4), block 256. (unchanged)
__global__ void nl75_refsc(const float* yIn, const float* rW, const float* rB,
                           const float* pc, float* outP, int bOff, int nb,
                           int ksplit) {
  __shared__ float rwS[32][66];
  __shared__ float yS[NL75_MID][132];  // reused as outS[8][516] after GEMM
  const int bl = blockIdx.x, cg = blockIdx.y, t = blockIdx.z;
  const int b = bOff + bl, c0 = cg * 8, tid = threadIdx.x;
  for (int i = tid; i < 32 * NL75_MID; i += 256) {
    int oh = i >> 6, m = i & 63;
    rwS[oh][m] = rW[(long long)(t * 32 + oh) * NL75_MID + m];
  }
  if (ksplit == 1) {
    const float* yB0 = yIn + (size_t)bl * NL75_MID * NL75_TN;
    for (int i = tid; i < NL75_MID * 32; i += 256) {
      int m = i >> 5, r = i & 31;       // r = i16*2 + half
      int i16 = r >> 1, half = r & 1;
      const float4 v = *(const float4*)&yB0[(size_t)m * NL75_TN + i16 * 128 +
                                            c0 + half * 4];
      *(float4*)&yS[m][i16 * 8 + half * 4] = v;
    }
  } else {
    for (int i = tid; i < NL75_MID * 128; i += 256) {
      int m = i >> 7, qi = i & 127;
      int i16 = qi >> 3, cl = qi & 7;
      long long off = (long long)m * NL75_TN + i16 * 128 + c0 + cl;
      float v = 0.0f;
      for (int ks = 0; ks < ksplit; ks++)
        v += yIn[((long long)(ks * nb + bl) * NL75_MID) * NL75_TN + off];
      yS[m][qi] = v;
    }
  }
  __syncthreads();
  const int oh0 = (tid >> 5) * 4;
  const int q4 = (tid & 31) * 4;
  float acc[4][4];
#pragma unroll
  for (int i = 0; i < 4; i++) {
    float bias = rB[t * 32 + oh0 + i];
#pragma unroll
    for (int j = 0; j < 4; j++) acc[i][j] = bias;
  }
  for (int m = 0; m < NL75_MID; m++) {
    float yv[4];
#pragma unroll
    for (int j = 0; j < 4; j++) yv[j] = yS[m][q4 + j];
#pragma unroll
    for (int i = 0; i < 4; i++) {
      float w = rwS[oh0 + i][m];
#pragma unroll
      for (int j = 0; j < 4; j++) acc[i][j] = fmaf(w, yv[j], acc[i][j]);
    }
  }
  __syncthreads();  // all yS reads done before outS overwrite
  float* outS = &yS[0][0];
  const int NP = 516;
#pragma unroll
  for (int i = 0; i < 4; i++) {
    const int oh = oh0 + i;
#pragma unroll
    for (int j = 0; j < 4; j++) {
      const int qi = q4 + j;
      outS[(qi & 7) * NP + oh * 16 + (qi >> 3)] = fmaxf(acc[i][j], 0.0f);
    }
  }
  __syncthreads();
  const size_t obase = (((size_t)b * 128 + c0) * 4 + t) * 512;
#pragma unroll
  for (int ii = 0; ii < 4; ii++) {
    const int fi = ii * 256 + tid;
    const int cl = fi >> 7, n0 = (fi & 127) * 4;
    float4 v = *(const float4*)&outS[cl * NP + n0];
    const size_t gi = obase + (size_t)cl * 4 * 512 + n0;
    const float4 p = *(const float4*)&pc[gi];
    v.x += p.x; v.y += p.y; v.z += p.z; v.w += p.w;
    *(float4*)&outP[gi] = v;
  }
}

extern "C" void kernel_launch(void* const* d_in, const int* in_sizes, int n_in,
                              void* d_out, int out_size, void* d_ws, size_t ws_size,
                              hipStream_t stream) {
  const float* pc = (const float*)d_in[0];
  const float* tw = (const float*)d_in[1];
  const float* tb = (const float*)d_in[2];
  const float* pw = (const float*)d_in[3];
  const float* pb = (const float*)d_in[4];
  const float* gw = (const float*)d_in[5];
  const float* gb = (const float*)d_in[6];
  const float* rw = (const float*)d_in[7];
  const float* rb = (const float*)d_in[8];
  float* out = (float*)d_out;

  const size_t yPB = (size_t)NL75_MID * NL75_TN;  // floats
  auto need = [&](int nb, int qs, int ks) -> size_t {
    return (3ull * nb * NL75_TN * 64 * 2) +
           ((size_t)qs * nb * NL75_TN + ((size_t)ks * nb + nb) * yPB) * 4;
  };

  int nb, qsplit, ksplit;
  if (ws_size >= need(8, 8, 8))      { nb = 8; qsplit = 8; ksplit = 8; }
  else if (ws_size >= need(8, 1, 1)) { nb = 8; qsplit = 1; ksplit = 1; }
  else                               { nb = 1; qsplit = 1; ksplit = 1; }
  const int nloop = 8 / nb;

  unsigned short* thT = (unsigned short*)d_ws;
  unsigned short* phT = thT + (size_t)nb * NL75_TN * 64;
  unsigned short* gN = phT + (size_t)nb * NL75_TN * 64;
  float* Sp = (float*)(gN + (size_t)nb * NL75_MID * NL75_TN);
  float* yPart = Sp + (size_t)qsplit * nb * NL75_TN;
  float* yFull = (ksplit > 1) ? yPart + (size_t)ksplit * nb * yPB : yPart;

  for (int l = 0; l < nloop; l++) {
    const int bOff = l * nb;
    nl75_proj<<<dim3(nb, 3, 32), 256, 0, stream>>>(pc, tw, tb, pw, pb, gw, gb,
                                                   thT, phT, gN, bOff, nb);
    nl75_stats<<<dim3(nb, 16 * qsplit), 256, 0, stream>>>(thT, phT, Sp, nb,
                                                          qsplit);
    nl75_attn<<<dim3(16 * ksplit * nb), 512, 0, stream>>>(
        thT, phT, gN, Sp, yPart, nb, ksplit, qsplit);
    if (ksplit > 1) {
      nl75_yred<<<dim3(1024), 256, 0, stream>>>(yPart, yFull, nb, ksplit);
      nl75_refsc<<<dim3(nb, 16, 4), 256, 0, stream>>>(yFull, rw, rb, pc, out,
                                                      bOff, nb, 1);
    } else {
      nl75_refsc<<<dim3(nb, 16, 4), 256, 0, stream>>>(yPart, rw, rb, pc, out,
                                                      bOff, nb, 1);
    }
  }
}